// Round 15
// baseline (315.866 us; speedup 1.0000x reference)
//
#include <hip/hip_runtime.h>
#include <hip/hip_bf16.h>
#include <math.h>

#define B_    8
#define L_    2048
#define HID   768
#define D2    384
#define NUV   1792
#define R_    16384
#define SCALE 0.08838834764831845f  // 128^-0.5

typedef __attribute__((ext_vector_type(8))) short bf16x8;
typedef __attribute__((ext_vector_type(4))) float f32x4;
typedef unsigned int uint32;
typedef unsigned short ushort;

static __device__ __forceinline__ uint32 bfr(float x) {
    uint32 u = __float_as_uint(x);
    return (u + 0x7FFFu + ((u >> 16) & 1u)) >> 16;
}
static __device__ __forceinline__ uint32 pk2(float lo, float hi) {
    return bfr(lo) | (bfr(hi) << 16);
}
static __device__ __forceinline__ float bf2f(ushort u) {
    return __uint_as_float(((uint32)u) << 16);
}
static __device__ __forceinline__ float silu_f(float x) { return x / (1.0f + __expf(-x)); }

// ---------------------------------------------------------------------------
// Weight pre-transform: Thi/Tlo[n][k] = bf16 hi/lo split of W[k][n]
// ---------------------------------------------------------------------------
__global__ __launch_bounds__(256) void conv_w(const float* __restrict__ W,
                                              ushort* __restrict__ Thi,
                                              ushort* __restrict__ Tlo,
                                              int K, int N)
{
    int idx = blockIdx.x * 256 + threadIdx.x;
    if (idx >= K * N) return;
    int n = idx / K, k = idx - n * K;
    float x = W[(size_t)k * N + n];
    uint32 h = bfr(x);
    float hf = __uint_as_float(h << 16);
    Thi[idx] = (ushort)h;
    Tlo[idx] = (ushort)bfr(x - hf);
}

// ---------------------------------------------------------------------------
// x pre-convert: xhi[m][k] = bf16(x[m][k])
// ---------------------------------------------------------------------------
__global__ __launch_bounds__(256) void conv_x(const float* __restrict__ X,
                                              ushort* __restrict__ Xhi, int total)
{
    int idx = blockIdx.x * 256 + threadIdx.x;
    if (idx >= total) return;
    Xhi[idx] = (ushort)bfr(X[idx]);
}

// ---------------------------------------------------------------------------
// GEMM1 (2-pass): C = x @ W_uv via Ahi*(Bhi+Blo). A pre-converted bf16.
// Block 512 thr (8 waves), tile 128x128, BK=64, K=384. LDS 48KB.
// GAU epilogue: u->silu f32, v->silu bf16 transposed vT, q/k->bf16 qk.
// ---------------------------------------------------------------------------
__global__ __launch_bounds__(512, 4) void gemm1_2p(
    const ushort* __restrict__ Ahi,
    const ushort* __restrict__ BThi, const ushort* __restrict__ BTlo,
    float* __restrict__ u_buf, ushort* __restrict__ qk, ushort* __restrict__ vT)
{
    __shared__ unsigned char As[128 * 128];
    __shared__ unsigned char Bs[128 * 256];

    const int t  = threadIdx.x;
    const int w  = t >> 6;
    const int l  = t & 63;
    const int g  = l >> 4;
    const int li = l & 15;
    const int wr = w >> 1;
    const int wc = w & 1;
    const int m0 = blockIdx.y * 128;
    const int n0 = blockIdx.x * 128;

    f32x4 acc[2][4];
#pragma unroll
    for (int i = 0; i < 2; ++i)
#pragma unroll
        for (int j = 0; j < 4; ++j) acc[i][j] = (f32x4){0.f, 0.f, 0.f, 0.f};

    for (int k0 = 0; k0 < D2; k0 += 64) {
#pragma unroll
        for (int i = 0; i < 2; ++i) {
            int idx = t + i * 512;
            int row = idx >> 3;
            int c8  = idx & 7;
            uint4 v = *(const uint4*)(Ahi + (size_t)(m0 + row) * D2 + k0 + c8 * 8);
            *(uint4*)&As[row * 128 + ((c8 * 16) ^ ((row & 7) << 4))] = v;
        }
#pragma unroll
        for (int i = 0; i < 8; ++i) {
            int idx = t + i * 512;
            int c   = idx >> 5;
            int s8  = idx & 31;
            const ushort* src = (s8 < 16)
                ? (BThi + (long long)(n0 + c) * D2 + k0 + s8 * 4)
                : (BTlo + (long long)(n0 + c) * D2 + k0 + (s8 - 16) * 4);
            *(uint2*)&Bs[c * 256 + ((s8 * 8) ^ ((c & 7) << 4))] = *(const uint2*)src;
        }
        __syncthreads();

#pragma unroll
        for (int ks = 0; ks < 2; ++ks) {
            bf16x8 ah[2], bh[4], bl[4];
#pragma unroll
            for (int mi = 0; mi < 2; ++mi) {
                int row = wr * 32 + mi * 16 + li;
                ah[mi] = *(const bf16x8*)&As[row * 128 + ((ks * 64 + g * 16) ^ ((row & 7) << 4))];
            }
#pragma unroll
            for (int ni = 0; ni < 4; ++ni) {
                int col = wc * 64 + ni * 16 + li;
                int off = (ks * 64 + g * 16) ^ ((col & 7) << 4);
                bh[ni] = *(const bf16x8*)&Bs[col * 256 + off];
                bl[ni] = *(const bf16x8*)&Bs[col * 256 + 128 + off];
            }
#pragma unroll
            for (int mi = 0; mi < 2; ++mi)
#pragma unroll
                for (int ni = 0; ni < 4; ++ni) {
                    acc[mi][ni] = __builtin_amdgcn_mfma_f32_16x16x32_bf16(ah[mi], bh[ni], acc[mi][ni], 0, 0, 0);
                    acc[mi][ni] = __builtin_amdgcn_mfma_f32_16x16x32_bf16(ah[mi], bl[ni], acc[mi][ni], 0, 0, 0);
                }
        }
        __syncthreads();
    }

    if (n0 < 768) {
#pragma unroll
        for (int mi = 0; mi < 2; ++mi)
#pragma unroll
            for (int ni = 0; ni < 4; ++ni) {
                int col = n0 + wc * 64 + ni * 16 + li;
#pragma unroll
                for (int r = 0; r < 4; ++r) {
                    int row = m0 + wr * 32 + mi * 16 + g * 4 + r;
                    u_buf[(long long)row * 768 + col] = silu_f(acc[mi][ni][r]);
                }
            }
    } else if (n0 < 1536) {
        int bb = m0 >> 11;
        int llb = (m0 & 2047) + wr * 32 + g * 4;
#pragma unroll
        for (int mi = 0; mi < 2; ++mi) {
            int ll = llb + mi * 16;
#pragma unroll
            for (int ni = 0; ni < 4; ++ni) {
                int cv = n0 + wc * 64 + ni * 16 + li - 768;
                ushort* vb = vT + ((size_t)bb * 768 + cv) * 2048 + ll;
                *(uint32*)(vb)     = pk2(silu_f(acc[mi][ni][0]), silu_f(acc[mi][ni][1]));
                *(uint32*)(vb + 2) = pk2(silu_f(acc[mi][ni][2]), silu_f(acc[mi][ni][3]));
            }
        }
    } else {
#pragma unroll
        for (int mi = 0; mi < 2; ++mi)
#pragma unroll
            for (int ni = 0; ni < 4; ++ni) {
                int qcol = n0 + wc * 64 + ni * 16 + li - 1536;
#pragma unroll
                for (int r = 0; r < 4; ++r) {
                    int row = m0 + wr * 32 + mi * 16 + g * 4 + r;
                    qk[(size_t)row * 256 + qcol] = (ushort)bfr(acc[mi][ni][r]);
                }
            }
    }
}

// ---------------------------------------------------------------------------
// GEMM2 (3-pass, unchanged): C = gated(f32) @ W_out, split A in staging.
// ---------------------------------------------------------------------------
__global__ __launch_bounds__(512, 4) void gemm2_3p(
    const float* __restrict__ A, int lda,
    const ushort* __restrict__ BThi, const ushort* __restrict__ BTlo, int ldbt,
    float* __restrict__ C, int ldc, int K)
{
    __shared__ unsigned char As[128 * 256];
    __shared__ unsigned char Bs[128 * 256];

    const int t  = threadIdx.x;
    const int w  = t >> 6;
    const int l  = t & 63;
    const int g  = l >> 4;
    const int li = l & 15;
    const int wr = w >> 1;
    const int wc = w & 1;
    const int m0 = blockIdx.y * 128;
    const int n0 = blockIdx.x * 128;

    f32x4 acc[2][4];
#pragma unroll
    for (int i = 0; i < 2; ++i)
#pragma unroll
        for (int j = 0; j < 4; ++j) acc[i][j] = (f32x4){0.f, 0.f, 0.f, 0.f};

    for (int k0 = 0; k0 < K; k0 += 64) {
#pragma unroll
        for (int i = 0; i < 4; ++i) {
            int idx = t + i * 512;
            int r   = idx >> 4;
            int c16 = idx & 15;
            float4 v = *(const float4*)(A + (long long)(m0 + r) * lda + k0 + c16 * 4);
            uint2 h; h.x = pk2(v.x, v.y); h.y = pk2(v.z, v.w);
            float hx = __uint_as_float((h.x & 0xFFFFu) << 16), hy = __uint_as_float(h.x & 0xFFFF0000u);
            float hz = __uint_as_float((h.y & 0xFFFFu) << 16), hw = __uint_as_float(h.y & 0xFFFF0000u);
            uint2 lo; lo.x = pk2(v.x - hx, v.y - hy); lo.y = pk2(v.z - hz, v.w - hw);
            int sw = (c16 * 8) ^ ((r & 7) << 4);
            *(uint2*)&As[r * 256 + sw]       = h;
            *(uint2*)&As[r * 256 + 128 + sw] = lo;
        }
#pragma unroll
        for (int i = 0; i < 8; ++i) {
            int idx = t + i * 512;
            int c   = idx >> 5;
            int s8  = idx & 31;
            const ushort* src = (s8 < 16)
                ? (BThi + (long long)(n0 + c) * ldbt + k0 + s8 * 4)
                : (BTlo + (long long)(n0 + c) * ldbt + k0 + (s8 - 16) * 4);
            *(uint2*)&Bs[c * 256 + ((s8 * 8) ^ ((c & 7) << 4))] = *(const uint2*)src;
        }
        __syncthreads();

#pragma unroll
        for (int ks = 0; ks < 2; ++ks) {
            bf16x8 ah[2], al[2], bh[4], bl[4];
#pragma unroll
            for (int mi = 0; mi < 2; ++mi) {
                int row = wr * 32 + mi * 16 + li;
                int off = (ks * 64 + g * 16) ^ ((row & 7) << 4);
                ah[mi] = *(const bf16x8*)&As[row * 256 + off];
                al[mi] = *(const bf16x8*)&As[row * 256 + 128 + off];
            }
#pragma unroll
            for (int ni = 0; ni < 4; ++ni) {
                int col = wc * 64 + ni * 16 + li;
                int off = (ks * 64 + g * 16) ^ ((col & 7) << 4);
                bh[ni] = *(const bf16x8*)&Bs[col * 256 + off];
                bl[ni] = *(const bf16x8*)&Bs[col * 256 + 128 + off];
            }
#pragma unroll
            for (int mi = 0; mi < 2; ++mi)
#pragma unroll
                for (int ni = 0; ni < 4; ++ni) {
                    acc[mi][ni] = __builtin_amdgcn_mfma_f32_16x16x32_bf16(ah[mi], bh[ni], acc[mi][ni], 0, 0, 0);
                    acc[mi][ni] = __builtin_amdgcn_mfma_f32_16x16x32_bf16(ah[mi], bl[ni], acc[mi][ni], 0, 0, 0);
                    acc[mi][ni] = __builtin_amdgcn_mfma_f32_16x16x32_bf16(al[mi], bh[ni], acc[mi][ni], 0, 0, 0);
                }
        }
        __syncthreads();
    }

#pragma unroll
    for (int mi = 0; mi < 2; ++mi)
#pragma unroll
        for (int ni = 0; ni < 4; ++ni) {
            int col = n0 + wc * 64 + ni * 16 + li;
#pragma unroll
            for (int r = 0; r < 4; ++r) {
                int row = m0 + wr * 32 + mi * 16 + g * 4 + r;
                C[(long long)row * ldc + col] = acc[mi][ni][r];
            }
        }
}

// ---------------------------------------------------------------------------
// RoPE in place on bf16 qk buffer
// ---------------------------------------------------------------------------
__global__ __launch_bounds__(128) void rope_bf(ushort* __restrict__ qk,
                                               const float* __restrict__ pos)
{
    int row = blockIdx.x;
    int lpos = row & (L_ - 1);
    int t = threadIdx.x;
    int j = t & 63;
    int isK = t >> 6;
    ushort* base = qk + (size_t)row * 256 + isK * 128;
    float s = pos[lpos * 256 + j];
    float c = pos[lpos * 256 + 64 + j];
    float x1 = bf2f(base[j]);
    float x2 = bf2f(base[64 + j]);
    base[j]      = (ushort)bfr(x1 * c - x2 * s);
    base[64 + j] = (ushort)bfr(x2 * c + x1 * s);
}

// ---------------------------------------------------------------------------
// MFMA flash attention v11 — 16-wave re-partition of v10 for 4 waves/SIMD.
// QBLK=64, KVBLK=128, no-max softmax, 2 barriers/tile. Grid 256, 1024 thr.
// QK: wave w -> rtq=w>>2 (16 rows), kq=w&3 (32 keys = 2 ct), 2 chains.
// PV: wave w -> V-cols w*48..+48, o[4][3] (48 VGPR acc).
// Per-thread live ~120 regs -> 4 waves/SIMD (16 waves/CU resident).
// ---------------------------------------------------------------------------
__global__ __launch_bounds__(1024) void fused_attn11(
    float* __restrict__ u_buf, const ushort* __restrict__ qk,
    const ushort* __restrict__ vT)
{
    __shared__ unsigned char KbB[128 * 256];   // K tile bf16 [128 keys][128 d], swizzled
    __shared__ unsigned char PbB[64 * 256];    // P bf16 [64 rows][128 keys], swizzled
    __shared__ float lred[4][64];              // per-key-quarter row sums

    const int t  = threadIdx.x;
    const int w  = t >> 6;                     // wave 0..15
    const int l  = t & 63;
    const int g  = l >> 4;
    const int li = l & 15;

    const int b  = blockIdx.x & 7;             // XCD-pinned batch
    const int qt = blockIdx.x >> 3;            // 0..31
    const long long rowQ0 = (long long)b * L_ + (long long)qt * 64;
    const long long rowB0 = (long long)b * L_;

    const int rtq = w >> 2;                    // QK row-tile 0..3
    const int kq  = w & 3;                     // key quarter 0..3

    // Q A-fragments for rows rtq*16+li
    bf16x8 qf[4];
    {
        const ushort* qrow = qk + (rowQ0 + rtq * 16 + li) * 256;
#pragma unroll
        for (int ks = 0; ks < 4; ++ks)
            qf[ks] = *(const bf16x8*)&qrow[ks * 32 + g * 8];
    }

    float l_part[4] = {0.f, 0.f, 0.f, 0.f};    // rows rtq*16 + g*4 + r, this key quarter

    f32x4 o[4][3];
#pragma unroll
    for (int rt = 0; rt < 4; ++rt)
#pragma unroll
        for (int ct = 0; ct < 3; ++ct)
            o[rt][ct] = (f32x4){0.f, 0.f, 0.f, 0.f};

    const ushort* vrow = vT + ((size_t)b * 768 + w * 48 + li) * 2048 + g * 8;

    // K staging: thread (kr=t>>4 in 0..63, c16=t&15) stages keys kr, kr+64
    const int kr  = t >> 4;
    const int c16 = t & 15;
    const int ksw = (c16 * 16) ^ ((kr & 7) << 4);   // (kr+64)&7 == kr&7

    uint4 kA = *(const uint4*)&qk[(rowB0 + kr)      * 256 + 128 + c16 * 8];
    uint4 kB = *(const uint4*)&qk[(rowB0 + kr + 64) * 256 + 128 + c16 * 8];

    union U16 { uint4 u; bf16x8 bv; };

    for (int jt = 0; jt < 16; ++jt) {
        // ---- publish staged K tile ----
        *(uint4*)&KbB[(kr)      * 256 + ksw] = kA;
        *(uint4*)&KbB[(kr + 64) * 256 + ksw] = kB;
        __syncthreads();   // (A) K ready

        if (jt + 1 < 16) {
            const ushort* kn = qk + (rowB0 + (jt + 1) * 128) * 256 + 128 + c16 * 8;
            kA = *(const uint4*)(kn + (size_t)(kr)      * 256);
            kB = *(const uint4*)(kn + (size_t)(kr + 64) * 256);
        }

        // ---- QK: 2 S-tiles (rows rtq*16.., keys kq*32 + ci*16..) + exp + Pb ----
#pragma unroll
        for (int ci = 0; ci < 2; ++ci) {
            const int ct = kq * 2 + ci;
            const int krow = ct * 16 + li;
            const int rs = (krow & 7) << 4;
            f32x4 s = {0.f, 0.f, 0.f, 0.f};
#pragma unroll
            for (int ks = 0; ks < 4; ++ks) {
                bf16x8 kf = *(const bf16x8*)&KbB[krow * 256 + ((ks * 64 + g * 16) ^ rs)];
                s = __builtin_amdgcn_mfma_f32_16x16x32_bf16(qf[ks], kf, s, 0, 0, 0);
            }
#pragma unroll
            for (int r = 0; r < 4; ++r) {
                float p = __expf(SCALE * s[r]);
                l_part[r] += p;
                const int prow = rtq * 16 + g * 4 + r;
                *(ushort*)&PbB[prow * 256 + (((ct * 16 + li) * 2) ^ ((prow & 7) << 4))]
                    = (ushort)bfr(p);
            }
        }
        __syncthreads();   // (C) Pb ready

        // ---- PV: ks-outer; per ks: pa[4] + V[3] resident, 12 MFMA ----
        const ushort* vj = vrow + jt * 128;
#pragma unroll
        for (int ks = 0; ks < 4; ++ks) {
            bf16x8 pa0 = *(const bf16x8*)&PbB[(0 * 16 + li) * 256 + ((ks * 64 + g * 16) ^ ((li & 7) << 4))];
            bf16x8 pa1 = *(const bf16x8*)&PbB[(1 * 16 + li) * 256 + ((ks * 64 + g * 16) ^ ((li & 7) << 4))];
            bf16x8 pa2 = *(const bf16x8*)&PbB[(2 * 16 + li) * 256 + ((ks * 64 + g * 16) ^ ((li & 7) << 4))];
            bf16x8 pa3 = *(const bf16x8*)&PbB[(3 * 16 + li) * 256 + ((ks * 64 + g * 16) ^ ((li & 7) << 4))];
            U16 vc0, vc1, vc2;
            vc0.u = *(const uint4*)(vj + (size_t)(0 * 16) * 2048 + ks * 32);
            vc1.u = *(const uint4*)(vj + (size_t)(1 * 16) * 2048 + ks * 32);
            vc2.u = *(const uint4*)(vj + (size_t)(2 * 16) * 2048 + ks * 32);
#define PV_CT(CT, VC) \
            o[0][CT] = __builtin_amdgcn_mfma_f32_16x16x32_bf16(pa0, VC.bv, o[0][CT], 0, 0, 0); \
            o[1][CT] = __builtin_amdgcn_mfma_f32_16x16x32_bf16(pa1, VC.bv, o[1][CT], 0, 0, 0); \
            o[2][CT] = __builtin_amdgcn_mfma_f32_16x16x32_bf16(pa2, VC.bv, o[2][CT], 0, 0, 0); \
            o[3][CT] = __builtin_amdgcn_mfma_f32_16x16x32_bf16(pa3, VC.bv, o[3][CT], 0, 0, 0);
            PV_CT(0, vc0)
            PV_CT(1, vc1)
            PV_CT(2, vc2)
#undef PV_CT
        }
        // staging(jt+1) touches only KbB: all waves passed (C) => QK reads done.
        // Pb writes of jt+1 happen after (A,jt+1), i.e. after all PV(jt) reads.
    }

    // ---- l reduction: 16 li-lanes, then across the four key-quarters ----
#pragma unroll
    for (int r = 0; r < 4; ++r) {
#pragma unroll
        for (int off = 8; off >= 1; off >>= 1)
            l_part[r] += __shfl_xor(l_part[r], off);
    }
    if (li == 0) {
#pragma unroll
        for (int r = 0; r < 4; ++r)
            lred[kq][rtq * 16 + g * 4 + r] = l_part[r];
    }
    __syncthreads();

    // ---- finalize: /l, gate u in place ----
#pragma unroll
    for (int rt = 0; rt < 4; ++rt) {
#pragma unroll
        for (int r = 0; r < 4; ++r) {
            const int row = rt * 16 + g * 4 + r;
            float inv = 1.0f / (lred[0][row] + lred[1][row] + lred[2][row] + lred[3][row]);
            float* ub = u_buf + (rowQ0 + row) * 768;
#pragma unroll
            for (int ct = 0; ct < 3; ++ct) {
                int col = w * 48 + ct * 16 + li;
                ub[col] = o[rt][ct][r] * inv * ub[col];
            }
        }
    }
}

extern "C" void kernel_launch(void* const* d_in, const int* in_sizes, int n_in,
                              void* d_out, int out_size, void* d_ws, size_t ws_size,
                              hipStream_t stream)
{
    const float* x    = (const float*)d_in[0];   // [8,2048,384]
    const float* pos  = (const float*)d_in[1];   // [1,2048,256]
    const float* Wuv  = (const float*)d_in[2];   // [384,1792]
    const float* Wout = (const float*)d_in[3];   // [768,384]
    float* out = (float*)d_out;                  // [8,2048,384] f32

    float*  u_buf = (float*)d_ws;                        // 16384*768 f32
    ushort* qk    = (ushort*)(u_buf + (size_t)R_ * HID); // 16384*256 bf16
    ushort* vT    = qk + (size_t)R_ * 256;               // 8*768*2048 bf16
    ushort* WuvThi  = vT + (size_t)B_ * HID * L_;
    ushort* WuvTlo  = WuvThi + (size_t)NUV * D2;
    ushort* WoutThi = WuvTlo + (size_t)NUV * D2;
    ushort* WoutTlo = WoutThi + (size_t)D2 * HID;
    ushort* xhi     = WoutTlo + (size_t)D2 * HID;        // 16384*384 bf16

    size_t need = ((size_t)R_ * HID) * 4 +
                  ((size_t)R_ * 256 + (size_t)B_ * HID * L_ +
                   2 * (size_t)NUV * D2 + 2 * (size_t)D2 * HID +
                   (size_t)R_ * D2) * 2;
    if (ws_size < need) return;

    conv_w<<<dim3((D2 * NUV + 255) / 256), dim3(256), 0, stream>>>(Wuv, WuvThi, WuvTlo, D2, NUV);
    conv_w<<<dim3((HID * D2 + 255) / 256), dim3(256), 0, stream>>>(Wout, WoutThi, WoutTlo, HID, D2);
    conv_x<<<dim3((R_ * D2 + 255) / 256), dim3(256), 0, stream>>>(x, xhi, R_ * D2);

    gemm1_2p<<<dim3(NUV / 128, R_ / 128), dim3(512), 0, stream>>>(
        xhi, WuvThi, WuvTlo, u_buf, qk, vT);

    rope_bf<<<dim3(R_), dim3(128), 0, stream>>>(qk, pos);

    fused_attn11<<<dim3(256), dim3(1024), 0, stream>>>(u_buf, qk, vT);

    gemm2_3p<<<dim3(D2 / 128, R_ / 128), dim3(512), 0, stream>>>(
        u_buf, HID, WoutThi, WoutTlo, HID, out, D2, HID);
}

// Round 16
// 288.365 us; speedup vs baseline: 1.0954x; 1.0954x over previous
//
#include <hip/hip_runtime.h>
#include <hip/hip_bf16.h>
#include <math.h>

#define B_    8
#define L_    2048
#define HID   768
#define D2    384
#define NUV   1792
#define R_    16384
#define SCALE 0.08838834764831845f  // 128^-0.5

typedef __attribute__((ext_vector_type(8))) short bf16x8;
typedef __attribute__((ext_vector_type(4))) float f32x4;
typedef unsigned int uint32;
typedef unsigned short ushort;

static __device__ __forceinline__ uint32 bfr(float x) {
    uint32 u = __float_as_uint(x);
    return (u + 0x7FFFu + ((u >> 16) & 1u)) >> 16;
}
static __device__ __forceinline__ uint32 pk2(float lo, float hi) {
    return bfr(lo) | (bfr(hi) << 16);
}
static __device__ __forceinline__ float bf2f(ushort u) {
    return __uint_as_float(((uint32)u) << 16);
}
static __device__ __forceinline__ float silu_f(float x) { return x / (1.0f + __expf(-x)); }

// ---------------------------------------------------------------------------
// Weight pre-transform: Thi/Tlo[n][k] = bf16 hi/lo split of W[k][n]
// ---------------------------------------------------------------------------
__global__ __launch_bounds__(256) void conv_w(const float* __restrict__ W,
                                              ushort* __restrict__ Thi,
                                              ushort* __restrict__ Tlo,
                                              int K, int N)
{
    int idx = blockIdx.x * 256 + threadIdx.x;
    if (idx >= K * N) return;
    int n = idx / K, k = idx - n * K;
    float x = W[(size_t)k * N + n];
    uint32 h = bfr(x);
    float hf = __uint_as_float(h << 16);
    Thi[idx] = (ushort)h;
    Tlo[idx] = (ushort)bfr(x - hf);
}

// ---------------------------------------------------------------------------
// x pre-convert: xhi[m][k] = bf16(x[m][k])
// ---------------------------------------------------------------------------
__global__ __launch_bounds__(256) void conv_x(const float* __restrict__ X,
                                              ushort* __restrict__ Xhi, int total)
{
    int idx = blockIdx.x * 256 + threadIdx.x;
    if (idx >= total) return;
    Xhi[idx] = (ushort)bfr(X[idx]);
}

// ---------------------------------------------------------------------------
// GEMM1 (2-pass): C = x @ W_uv via Ahi*(Bhi+Blo). A pre-converted bf16.
// ---------------------------------------------------------------------------
__global__ __launch_bounds__(512, 4) void gemm1_2p(
    const ushort* __restrict__ Ahi,
    const ushort* __restrict__ BThi, const ushort* __restrict__ BTlo,
    float* __restrict__ u_buf, ushort* __restrict__ qk, ushort* __restrict__ vT)
{
    __shared__ unsigned char As[128 * 128];
    __shared__ unsigned char Bs[128 * 256];

    const int t  = threadIdx.x;
    const int w  = t >> 6;
    const int l  = t & 63;
    const int g  = l >> 4;
    const int li = l & 15;
    const int wr = w >> 1;
    const int wc = w & 1;
    const int m0 = blockIdx.y * 128;
    const int n0 = blockIdx.x * 128;

    f32x4 acc[2][4];
#pragma unroll
    for (int i = 0; i < 2; ++i)
#pragma unroll
        for (int j = 0; j < 4; ++j) acc[i][j] = (f32x4){0.f, 0.f, 0.f, 0.f};

    for (int k0 = 0; k0 < D2; k0 += 64) {
#pragma unroll
        for (int i = 0; i < 2; ++i) {
            int idx = t + i * 512;
            int row = idx >> 3;
            int c8  = idx & 7;
            uint4 v = *(const uint4*)(Ahi + (size_t)(m0 + row) * D2 + k0 + c8 * 8);
            *(uint4*)&As[row * 128 + ((c8 * 16) ^ ((row & 7) << 4))] = v;
        }
#pragma unroll
        for (int i = 0; i < 8; ++i) {
            int idx = t + i * 512;
            int c   = idx >> 5;
            int s8  = idx & 31;
            const ushort* src = (s8 < 16)
                ? (BThi + (long long)(n0 + c) * D2 + k0 + s8 * 4)
                : (BTlo + (long long)(n0 + c) * D2 + k0 + (s8 - 16) * 4);
            *(uint2*)&Bs[c * 256 + ((s8 * 8) ^ ((c & 7) << 4))] = *(const uint2*)src;
        }
        __syncthreads();

#pragma unroll
        for (int ks = 0; ks < 2; ++ks) {
            bf16x8 ah[2], bh[4], bl[4];
#pragma unroll
            for (int mi = 0; mi < 2; ++mi) {
                int row = wr * 32 + mi * 16 + li;
                ah[mi] = *(const bf16x8*)&As[row * 128 + ((ks * 64 + g * 16) ^ ((row & 7) << 4))];
            }
#pragma unroll
            for (int ni = 0; ni < 4; ++ni) {
                int col = wc * 64 + ni * 16 + li;
                int off = (ks * 64 + g * 16) ^ ((col & 7) << 4);
                bh[ni] = *(const bf16x8*)&Bs[col * 256 + off];
                bl[ni] = *(const bf16x8*)&Bs[col * 256 + 128 + off];
            }
#pragma unroll
            for (int mi = 0; mi < 2; ++mi)
#pragma unroll
                for (int ni = 0; ni < 4; ++ni) {
                    acc[mi][ni] = __builtin_amdgcn_mfma_f32_16x16x32_bf16(ah[mi], bh[ni], acc[mi][ni], 0, 0, 0);
                    acc[mi][ni] = __builtin_amdgcn_mfma_f32_16x16x32_bf16(ah[mi], bl[ni], acc[mi][ni], 0, 0, 0);
                }
        }
        __syncthreads();
    }

    if (n0 < 768) {
#pragma unroll
        for (int mi = 0; mi < 2; ++mi)
#pragma unroll
            for (int ni = 0; ni < 4; ++ni) {
                int col = n0 + wc * 64 + ni * 16 + li;
#pragma unroll
                for (int r = 0; r < 4; ++r) {
                    int row = m0 + wr * 32 + mi * 16 + g * 4 + r;
                    u_buf[(long long)row * 768 + col] = silu_f(acc[mi][ni][r]);
                }
            }
    } else if (n0 < 1536) {
        int bb = m0 >> 11;
        int llb = (m0 & 2047) + wr * 32 + g * 4;
#pragma unroll
        for (int mi = 0; mi < 2; ++mi) {
            int ll = llb + mi * 16;
#pragma unroll
            for (int ni = 0; ni < 4; ++ni) {
                int cv = n0 + wc * 64 + ni * 16 + li - 768;
                ushort* vb = vT + ((size_t)bb * 768 + cv) * 2048 + ll;
                *(uint32*)(vb)     = pk2(silu_f(acc[mi][ni][0]), silu_f(acc[mi][ni][1]));
                *(uint32*)(vb + 2) = pk2(silu_f(acc[mi][ni][2]), silu_f(acc[mi][ni][3]));
            }
        }
    } else {
#pragma unroll
        for (int mi = 0; mi < 2; ++mi)
#pragma unroll
            for (int ni = 0; ni < 4; ++ni) {
                int qcol = n0 + wc * 64 + ni * 16 + li - 1536;
#pragma unroll
                for (int r = 0; r < 4; ++r) {
                    int row = m0 + wr * 32 + mi * 16 + g * 4 + r;
                    qk[(size_t)row * 256 + qcol] = (ushort)bfr(acc[mi][ni][r]);
                }
            }
    }
}

// ---------------------------------------------------------------------------
// GEMM2 (3-pass, unchanged): C = gated(f32) @ W_out, split A in staging.
// ---------------------------------------------------------------------------
__global__ __launch_bounds__(512, 4) void gemm2_3p(
    const float* __restrict__ A, int lda,
    const ushort* __restrict__ BThi, const ushort* __restrict__ BTlo, int ldbt,
    float* __restrict__ C, int ldc, int K)
{
    __shared__ unsigned char As[128 * 256];
    __shared__ unsigned char Bs[128 * 256];

    const int t  = threadIdx.x;
    const int w  = t >> 6;
    const int l  = t & 63;
    const int g  = l >> 4;
    const int li = l & 15;
    const int wr = w >> 1;
    const int wc = w & 1;
    const int m0 = blockIdx.y * 128;
    const int n0 = blockIdx.x * 128;

    f32x4 acc[2][4];
#pragma unroll
    for (int i = 0; i < 2; ++i)
#pragma unroll
        for (int j = 0; j < 4; ++j) acc[i][j] = (f32x4){0.f, 0.f, 0.f, 0.f};

    for (int k0 = 0; k0 < K; k0 += 64) {
#pragma unroll
        for (int i = 0; i < 4; ++i) {
            int idx = t + i * 512;
            int r   = idx >> 4;
            int c16 = idx & 15;
            float4 v = *(const float4*)(A + (long long)(m0 + r) * lda + k0 + c16 * 4);
            uint2 h; h.x = pk2(v.x, v.y); h.y = pk2(v.z, v.w);
            float hx = __uint_as_float((h.x & 0xFFFFu) << 16), hy = __uint_as_float(h.x & 0xFFFF0000u);
            float hz = __uint_as_float((h.y & 0xFFFFu) << 16), hw = __uint_as_float(h.y & 0xFFFF0000u);
            uint2 lo; lo.x = pk2(v.x - hx, v.y - hy); lo.y = pk2(v.z - hz, v.w - hw);
            int sw = (c16 * 8) ^ ((r & 7) << 4);
            *(uint2*)&As[r * 256 + sw]       = h;
            *(uint2*)&As[r * 256 + 128 + sw] = lo;
        }
#pragma unroll
        for (int i = 0; i < 8; ++i) {
            int idx = t + i * 512;
            int c   = idx >> 5;
            int s8  = idx & 31;
            const ushort* src = (s8 < 16)
                ? (BThi + (long long)(n0 + c) * ldbt + k0 + s8 * 4)
                : (BTlo + (long long)(n0 + c) * ldbt + k0 + (s8 - 16) * 4);
            *(uint2*)&Bs[c * 256 + ((s8 * 8) ^ ((c & 7) << 4))] = *(const uint2*)src;
        }
        __syncthreads();

#pragma unroll
        for (int ks = 0; ks < 2; ++ks) {
            bf16x8 ah[2], al[2], bh[4], bl[4];
#pragma unroll
            for (int mi = 0; mi < 2; ++mi) {
                int row = wr * 32 + mi * 16 + li;
                int off = (ks * 64 + g * 16) ^ ((row & 7) << 4);
                ah[mi] = *(const bf16x8*)&As[row * 256 + off];
                al[mi] = *(const bf16x8*)&As[row * 256 + 128 + off];
            }
#pragma unroll
            for (int ni = 0; ni < 4; ++ni) {
                int col = wc * 64 + ni * 16 + li;
                int off = (ks * 64 + g * 16) ^ ((col & 7) << 4);
                bh[ni] = *(const bf16x8*)&Bs[col * 256 + off];
                bl[ni] = *(const bf16x8*)&Bs[col * 256 + 128 + off];
            }
#pragma unroll
            for (int mi = 0; mi < 2; ++mi)
#pragma unroll
                for (int ni = 0; ni < 4; ++ni) {
                    acc[mi][ni] = __builtin_amdgcn_mfma_f32_16x16x32_bf16(ah[mi], bh[ni], acc[mi][ni], 0, 0, 0);
                    acc[mi][ni] = __builtin_amdgcn_mfma_f32_16x16x32_bf16(ah[mi], bl[ni], acc[mi][ni], 0, 0, 0);
                    acc[mi][ni] = __builtin_amdgcn_mfma_f32_16x16x32_bf16(al[mi], bh[ni], acc[mi][ni], 0, 0, 0);
                }
        }
        __syncthreads();
    }

#pragma unroll
    for (int mi = 0; mi < 2; ++mi)
#pragma unroll
        for (int ni = 0; ni < 4; ++ni) {
            int col = n0 + wc * 64 + ni * 16 + li;
#pragma unroll
            for (int r = 0; r < 4; ++r) {
                int row = m0 + wr * 32 + mi * 16 + g * 4 + r;
                C[(long long)row * ldc + col] = acc[mi][ni][r];
            }
        }
}

// ---------------------------------------------------------------------------
// RoPE in place on bf16 qk buffer
// ---------------------------------------------------------------------------
__global__ __launch_bounds__(128) void rope_bf(ushort* __restrict__ qk,
                                               const float* __restrict__ pos)
{
    int row = blockIdx.x;
    int lpos = row & (L_ - 1);
    int t = threadIdx.x;
    int j = t & 63;
    int isK = t >> 6;
    ushort* base = qk + (size_t)row * 256 + isK * 128;
    float s = pos[lpos * 256 + j];
    float c = pos[lpos * 256 + 64 + j];
    float x1 = bf2f(base[j]);
    float x2 = bf2f(base[64 + j]);
    base[j]      = (ushort)bfr(x1 * c - x2 * s);
    base[64 + j] = (ushort)bfr(x2 * c + x1 * s);
}

// ---------------------------------------------------------------------------
// MFMA flash attention v12 = r14's v10 with the 768 V-cols split across 2
// blocks (sp): o[4][6] -> o[4][3] (acc 96->48 regs), grid 512, 512 thr.
// Per-thread live state ~126 regs -> 3-4 waves/SIMD (was 2).
// QBLK=64, KVBLK=128, no-max softmax, 2 barriers/tile — all r14-verified.
// ---------------------------------------------------------------------------
__global__ __launch_bounds__(512) void fused_attn12(
    float* __restrict__ u_buf, const ushort* __restrict__ qk,
    const ushort* __restrict__ vT)
{
    __shared__ unsigned char KbB[128 * 256];   // K tile bf16 [128 keys][128 d], swizzled
    __shared__ unsigned char PbB[64 * 256];    // P bf16 [64 rows][128 keys], swizzled
    __shared__ float lred[2][64];

    const int t  = threadIdx.x;
    const int w  = t >> 6;
    const int l  = t & 63;
    const int g  = l >> 4;
    const int li = l & 15;

    const int blk = blockIdx.x;
    const int b   = blk & 7;                   // XCD-pinned batch
    const int sp  = (blk >> 3) & 1;            // V-column half
    const int qt  = blk >> 4;                  // 0..31
    const long long rowQ0 = (long long)b * L_ + (long long)qt * 64;
    const long long rowB0 = (long long)b * L_;

    const int rtq = w >> 1;                    // QK row-tile 0..3
    const int ch  = w & 1;                     // key half 0..1

    bf16x8 qf[4];
    {
        const ushort* qrow = qk + (rowQ0 + rtq * 16 + li) * 256;
#pragma unroll
        for (int ks = 0; ks < 4; ++ks)
            qf[ks] = *(const bf16x8*)&qrow[ks * 32 + g * 8];
    }

    float l_part[4] = {0.f, 0.f, 0.f, 0.f};

    f32x4 o[4][3];
#pragma unroll
    for (int rt = 0; rt < 4; ++rt)
#pragma unroll
        for (int ct = 0; ct < 3; ++ct)
            o[rt][ct] = (f32x4){0.f, 0.f, 0.f, 0.f};

    // this block's 48-col wave slice inside its 384-col half
    const ushort* vrow = vT + ((size_t)b * 768 + sp * 384 + w * 48 + li) * 2048 + g * 8;

    const int kr  = t >> 4;
    const int c16 = t & 15;
    const int ksw = (c16 * 16) ^ ((kr & 7) << 4);

    uint4 kA = *(const uint4*)&qk[(rowB0 + kr)      * 256 + 128 + c16 * 8];
    uint4 kB = *(const uint4*)&qk[(rowB0 + kr + 32) * 256 + 128 + c16 * 8];
    uint4 kC = *(const uint4*)&qk[(rowB0 + kr + 64) * 256 + 128 + c16 * 8];
    uint4 kD = *(const uint4*)&qk[(rowB0 + kr + 96) * 256 + 128 + c16 * 8];

    union U16 { uint4 u; bf16x8 bv; };

    for (int jt = 0; jt < 16; ++jt) {
        *(uint4*)&KbB[(kr)      * 256 + ksw] = kA;
        *(uint4*)&KbB[(kr + 32) * 256 + ksw] = kB;
        *(uint4*)&KbB[(kr + 64) * 256 + ksw] = kC;
        *(uint4*)&KbB[(kr + 96) * 256 + ksw] = kD;
        __syncthreads();   // (A) K ready

        if (jt + 1 < 16) {
            const ushort* kn = qk + (rowB0 + (jt + 1) * 128) * 256 + 128 + c16 * 8;
            kA = *(const uint4*)(kn + (size_t)(kr)      * 256);
            kB = *(const uint4*)(kn + (size_t)(kr + 32) * 256);
            kC = *(const uint4*)(kn + (size_t)(kr + 64) * 256);
            kD = *(const uint4*)(kn + (size_t)(kr + 96) * 256);
        }

        // ---- QK: 4 S-tiles (rows rtq*16.., keys ch*64 + ci*16..) + exp + Pb ----
#pragma unroll
        for (int ci = 0; ci < 4; ++ci) {
            const int ct = ch * 4 + ci;
            const int krow = ct * 16 + li;
            const int rs = (krow & 7) << 4;
            f32x4 s = {0.f, 0.f, 0.f, 0.f};
#pragma unroll
            for (int ks = 0; ks < 4; ++ks) {
                bf16x8 kf = *(const bf16x8*)&KbB[krow * 256 + ((ks * 64 + g * 16) ^ rs)];
                s = __builtin_amdgcn_mfma_f32_16x16x32_bf16(qf[ks], kf, s, 0, 0, 0);
            }
#pragma unroll
            for (int r = 0; r < 4; ++r) {
                float p = __expf(SCALE * s[r]);
                l_part[r] += p;
                const int prow = rtq * 16 + g * 4 + r;
                *(ushort*)&PbB[prow * 256 + (((ct * 16 + li) * 2) ^ ((prow & 7) << 4))]
                    = (ushort)bfr(p);
            }
        }
        __syncthreads();   // (C) Pb ready

        // ---- PV: ks-outer; per ks: pa[4] + V[3] resident, 12 MFMA ----
        const ushort* vj = vrow + jt * 128;
#pragma unroll
        for (int ks = 0; ks < 4; ++ks) {
            bf16x8 pa0 = *(const bf16x8*)&PbB[(0 * 16 + li) * 256 + ((ks * 64 + g * 16) ^ ((li & 7) << 4))];
            bf16x8 pa1 = *(const bf16x8*)&PbB[(1 * 16 + li) * 256 + ((ks * 64 + g * 16) ^ ((li & 7) << 4))];
            bf16x8 pa2 = *(const bf16x8*)&PbB[(2 * 16 + li) * 256 + ((ks * 64 + g * 16) ^ ((li & 7) << 4))];
            bf16x8 pa3 = *(const bf16x8*)&PbB[(3 * 16 + li) * 256 + ((ks * 64 + g * 16) ^ ((li & 7) << 4))];
            U16 vc0, vc1, vc2;
            vc0.u = *(const uint4*)(vj + (size_t)(0 * 16) * 2048 + ks * 32);
            vc1.u = *(const uint4*)(vj + (size_t)(1 * 16) * 2048 + ks * 32);
            vc2.u = *(const uint4*)(vj + (size_t)(2 * 16) * 2048 + ks * 32);
#define PV_CT(CT, VC) \
            o[0][CT] = __builtin_amdgcn_mfma_f32_16x16x32_bf16(pa0, VC.bv, o[0][CT], 0, 0, 0); \
            o[1][CT] = __builtin_amdgcn_mfma_f32_16x16x32_bf16(pa1, VC.bv, o[1][CT], 0, 0, 0); \
            o[2][CT] = __builtin_amdgcn_mfma_f32_16x16x32_bf16(pa2, VC.bv, o[2][CT], 0, 0, 0); \
            o[3][CT] = __builtin_amdgcn_mfma_f32_16x16x32_bf16(pa3, VC.bv, o[3][CT], 0, 0, 0);
            PV_CT(0, vc0)
            PV_CT(1, vc1)
            PV_CT(2, vc2)
#undef PV_CT
        }
    }

    // ---- l reduction ----
#pragma unroll
    for (int r = 0; r < 4; ++r) {
#pragma unroll
        for (int off = 8; off >= 1; off >>= 1)
            l_part[r] += __shfl_xor(l_part[r], off);
    }
    if (li == 0) {
#pragma unroll
        for (int r = 0; r < 4; ++r)
            lred[ch][rtq * 16 + g * 4 + r] = l_part[r];
    }
    __syncthreads();

    // ---- finalize: /l, gate u in place (disjoint 384-col half) ----
#pragma unroll
    for (int rt = 0; rt < 4; ++rt) {
#pragma unroll
        for (int r = 0; r < 4; ++r) {
            const int row = rt * 16 + g * 4 + r;
            float inv = 1.0f / (lred[0][row] + lred[1][row]);
            float* ub = u_buf + (rowQ0 + row) * 768;
#pragma unroll
            for (int ct = 0; ct < 3; ++ct) {
                int col = sp * 384 + w * 48 + ct * 16 + li;
                ub[col] = o[rt][ct][r] * inv * ub[col];
            }
        }
    }
}

extern "C" void kernel_launch(void* const* d_in, const int* in_sizes, int n_in,
                              void* d_out, int out_size, void* d_ws, size_t ws_size,
                              hipStream_t stream)
{
    const float* x    = (const float*)d_in[0];   // [8,2048,384]
    const float* pos  = (const float*)d_in[1];   // [1,2048,256]
    const float* Wuv  = (const float*)d_in[2];   // [384,1792]
    const float* Wout = (const float*)d_in[3];   // [768,384]
    float* out = (float*)d_out;                  // [8,2048,384] f32

    float*  u_buf = (float*)d_ws;                        // 16384*768 f32
    ushort* qk    = (ushort*)(u_buf + (size_t)R_ * HID); // 16384*256 bf16
    ushort* vT    = qk + (size_t)R_ * 256;               // 8*768*2048 bf16
    ushort* WuvThi  = vT + (size_t)B_ * HID * L_;
    ushort* WuvTlo  = WuvThi + (size_t)NUV * D2;
    ushort* WoutThi = WuvTlo + (size_t)NUV * D2;
    ushort* WoutTlo = WoutThi + (size_t)D2 * HID;
    ushort* xhi     = WoutTlo + (size_t)D2 * HID;        // 16384*384 bf16

    size_t need = ((size_t)R_ * HID) * 4 +
                  ((size_t)R_ * 256 + (size_t)B_ * HID * L_ +
                   2 * (size_t)NUV * D2 + 2 * (size_t)D2 * HID +
                   (size_t)R_ * D2) * 2;
    if (ws_size < need) return;

    conv_w<<<dim3((D2 * NUV + 255) / 256), dim3(256), 0, stream>>>(Wuv, WuvThi, WuvTlo, D2, NUV);
    conv_w<<<dim3((HID * D2 + 255) / 256), dim3(256), 0, stream>>>(Wout, WoutThi, WoutTlo, HID, D2);
    conv_x<<<dim3((R_ * D2 + 255) / 256), dim3(256), 0, stream>>>(x, xhi, R_ * D2);

    gemm1_2p<<<dim3(NUV / 128, R_ / 128), dim3(512), 0, stream>>>(
        xhi, WuvThi, WuvTlo, u_buf, qk, vT);

    rope_bf<<<dim3(R_), dim3(128), 0, stream>>>(qk, pos);

    fused_attn12<<<dim3(512), dim3(512), 0, stream>>>(u_buf, qk, vT);

    gemm2_3p<<<dim3(D2 / 128, R_ / 128), dim3(512), 0, stream>>>(
        u_buf, HID, WoutThi, WoutTlo, HID, out, D2, HID);
}

// Round 17
// 240.791 us; speedup vs baseline: 1.3118x; 1.1976x over previous
//
#include <hip/hip_runtime.h>
#include <hip/hip_bf16.h>
#include <math.h>

#define B_    8
#define L_    2048
#define HID   768
#define D2    384
#define NUV   1792
#define R_    16384
#define SCALE 0.08838834764831845f  // 128^-0.5

typedef __attribute__((ext_vector_type(8))) short bf16x8;
typedef __attribute__((ext_vector_type(4))) float f32x4;
typedef unsigned int uint32;
typedef unsigned short ushort;

static __device__ __forceinline__ uint32 bfr(float x) {
    uint32 u = __float_as_uint(x);
    return (u + 0x7FFFu + ((u >> 16) & 1u)) >> 16;
}
static __device__ __forceinline__ uint32 pk2(float lo, float hi) {
    return bfr(lo) | (bfr(hi) << 16);
}
static __device__ __forceinline__ float bf2f(ushort u) {
    return __uint_as_float(((uint32)u) << 16);
}
static __device__ __forceinline__ float silu_f(float x) { return x / (1.0f + __expf(-x)); }

// ---------------------------------------------------------------------------
// Weight pre-transform: Thi/Tlo[n][k] = bf16 hi/lo split of W[k][n]
// ---------------------------------------------------------------------------
__global__ __launch_bounds__(256) void conv_w(const float* __restrict__ W,
                                              ushort* __restrict__ Thi,
                                              ushort* __restrict__ Tlo,
                                              int K, int N)
{
    int idx = blockIdx.x * 256 + threadIdx.x;
    if (idx >= K * N) return;
    int n = idx / K, k = idx - n * K;
    float x = W[(size_t)k * N + n];
    uint32 h = bfr(x);
    float hf = __uint_as_float(h << 16);
    Thi[idx] = (ushort)h;
    Tlo[idx] = (ushort)bfr(x - hf);
}

// ---------------------------------------------------------------------------
// x pre-convert: xhi[m][k] = bf16(x[m][k])
// ---------------------------------------------------------------------------
__global__ __launch_bounds__(256) void conv_x(const float* __restrict__ X,
                                              ushort* __restrict__ Xhi, int total)
{
    int idx = blockIdx.x * 256 + threadIdx.x;
    if (idx >= total) return;
    Xhi[idx] = (ushort)bfr(X[idx]);
}

// ---------------------------------------------------------------------------
// Bf16-A 2-pass GEMM core: C_f32 = Abf16 @ (Bhi + Blo), copy staging.
// Block 512 thr (8 waves), tile 128x128, BK=64. LDS 48KB.
// EPI 0: plain f32 C.  EPI 1: GAU GEMM1 epilogue (u/v/qk by n0).
// ---------------------------------------------------------------------------
template<int EPI>
__global__ __launch_bounds__(512, 4) void gemm_2p(
    const ushort* __restrict__ Ahi, int lda,
    const ushort* __restrict__ BThi, const ushort* __restrict__ BTlo, int ldbt,
    float* __restrict__ C, int ldc,
    float* __restrict__ u_buf, ushort* __restrict__ qk, ushort* __restrict__ vT,
    int K)
{
    __shared__ unsigned char As[128 * 128];
    __shared__ unsigned char Bs[128 * 256];

    const int t  = threadIdx.x;
    const int w  = t >> 6;
    const int l  = t & 63;
    const int g  = l >> 4;
    const int li = l & 15;
    const int wr = w >> 1;
    const int wc = w & 1;
    const int m0 = blockIdx.y * 128;
    const int n0 = blockIdx.x * 128;

    f32x4 acc[2][4];
#pragma unroll
    for (int i = 0; i < 2; ++i)
#pragma unroll
        for (int j = 0; j < 4; ++j) acc[i][j] = (f32x4){0.f, 0.f, 0.f, 0.f};

    for (int k0 = 0; k0 < K; k0 += 64) {
        // stage A: copy 128x64 bf16 (16KB)
#pragma unroll
        for (int i = 0; i < 2; ++i) {
            int idx = t + i * 512;
            int row = idx >> 3;
            int c8  = idx & 7;
            uint4 v = *(const uint4*)(Ahi + (size_t)(m0 + row) * lda + k0 + c8 * 8);
            *(uint4*)&As[row * 128 + ((c8 * 16) ^ ((row & 7) << 4))] = v;
        }
        // stage B: copy pre-split hi/lo rows (32KB)
#pragma unroll
        for (int i = 0; i < 8; ++i) {
            int idx = t + i * 512;
            int c   = idx >> 5;
            int s8  = idx & 31;
            const ushort* src = (s8 < 16)
                ? (BThi + (long long)(n0 + c) * ldbt + k0 + s8 * 4)
                : (BTlo + (long long)(n0 + c) * ldbt + k0 + (s8 - 16) * 4);
            *(uint2*)&Bs[c * 256 + ((s8 * 8) ^ ((c & 7) << 4))] = *(const uint2*)src;
        }
        __syncthreads();

#pragma unroll
        for (int ks = 0; ks < 2; ++ks) {
            bf16x8 ah[2], bh[4], bl[4];
#pragma unroll
            for (int mi = 0; mi < 2; ++mi) {
                int row = wr * 32 + mi * 16 + li;
                ah[mi] = *(const bf16x8*)&As[row * 128 + ((ks * 64 + g * 16) ^ ((row & 7) << 4))];
            }
#pragma unroll
            for (int ni = 0; ni < 4; ++ni) {
                int col = wc * 64 + ni * 16 + li;
                int off = (ks * 64 + g * 16) ^ ((col & 7) << 4);
                bh[ni] = *(const bf16x8*)&Bs[col * 256 + off];
                bl[ni] = *(const bf16x8*)&Bs[col * 256 + 128 + off];
            }
#pragma unroll
            for (int mi = 0; mi < 2; ++mi)
#pragma unroll
                for (int ni = 0; ni < 4; ++ni) {
                    acc[mi][ni] = __builtin_amdgcn_mfma_f32_16x16x32_bf16(ah[mi], bh[ni], acc[mi][ni], 0, 0, 0);
                    acc[mi][ni] = __builtin_amdgcn_mfma_f32_16x16x32_bf16(ah[mi], bl[ni], acc[mi][ni], 0, 0, 0);
                }
        }
        __syncthreads();
    }

    if (EPI == 0) {
#pragma unroll
        for (int mi = 0; mi < 2; ++mi)
#pragma unroll
            for (int ni = 0; ni < 4; ++ni) {
                int col = n0 + wc * 64 + ni * 16 + li;
#pragma unroll
                for (int r = 0; r < 4; ++r) {
                    int row = m0 + wr * 32 + mi * 16 + g * 4 + r;
                    C[(long long)row * ldc + col] = acc[mi][ni][r];
                }
            }
    } else {
        if (n0 < 768) {
#pragma unroll
            for (int mi = 0; mi < 2; ++mi)
#pragma unroll
                for (int ni = 0; ni < 4; ++ni) {
                    int col = n0 + wc * 64 + ni * 16 + li;
#pragma unroll
                    for (int r = 0; r < 4; ++r) {
                        int row = m0 + wr * 32 + mi * 16 + g * 4 + r;
                        u_buf[(long long)row * 768 + col] = silu_f(acc[mi][ni][r]);
                    }
                }
        } else if (n0 < 1536) {
            int bb = m0 >> 11;
            int llb = (m0 & 2047) + wr * 32 + g * 4;
#pragma unroll
            for (int mi = 0; mi < 2; ++mi) {
                int ll = llb + mi * 16;
#pragma unroll
                for (int ni = 0; ni < 4; ++ni) {
                    int cv = n0 + wc * 64 + ni * 16 + li - 768;
                    ushort* vb = vT + ((size_t)bb * 768 + cv) * 2048 + ll;
                    *(uint32*)(vb)     = pk2(silu_f(acc[mi][ni][0]), silu_f(acc[mi][ni][1]));
                    *(uint32*)(vb + 2) = pk2(silu_f(acc[mi][ni][2]), silu_f(acc[mi][ni][3]));
                }
            }
        } else {
#pragma unroll
            for (int mi = 0; mi < 2; ++mi)
#pragma unroll
                for (int ni = 0; ni < 4; ++ni) {
                    int qcol = n0 + wc * 64 + ni * 16 + li - 1536;
#pragma unroll
                    for (int r = 0; r < 4; ++r) {
                        int row = m0 + wr * 32 + mi * 16 + g * 4 + r;
                        qk[(size_t)row * 256 + qcol] = (ushort)bfr(acc[mi][ni][r]);
                    }
                }
        }
    }
}

// ---------------------------------------------------------------------------
// RoPE in place on bf16 qk buffer
// ---------------------------------------------------------------------------
__global__ __launch_bounds__(128) void rope_bf(ushort* __restrict__ qk,
                                               const float* __restrict__ pos)
{
    int row = blockIdx.x;
    int lpos = row & (L_ - 1);
    int t = threadIdx.x;
    int j = t & 63;
    int isK = t >> 6;
    ushort* base = qk + (size_t)row * 256 + isK * 128;
    float s = pos[lpos * 256 + j];
    float c = pos[lpos * 256 + 64 + j];
    float x1 = bf2f(base[j]);
    float x2 = bf2f(base[64 + j]);
    base[j]      = (ushort)bfr(x1 * c - x2 * s);
    base[64 + j] = (ushort)bfr(x2 * c + x1 * s);
}

// ---------------------------------------------------------------------------
// MFMA flash attention v13 = r14's v10 (best, unchanged body) except the
// finalize: gated result written as bf16 to `gated` (u_buf read-only).
// QBLK=64, KVBLK=128, no-max softmax, 2 barriers/tile. Grid 256, 512 thr.
// ---------------------------------------------------------------------------
__global__ __launch_bounds__(512) void fused_attn13(
    const float* __restrict__ u_buf, const ushort* __restrict__ qk,
    const ushort* __restrict__ vT, ushort* __restrict__ gated)
{
    __shared__ unsigned char KbB[128 * 256];
    __shared__ unsigned char PbB[64 * 256];
    __shared__ float lred[2][64];

    const int t  = threadIdx.x;
    const int w  = t >> 6;
    const int l  = t & 63;
    const int g  = l >> 4;
    const int li = l & 15;

    const int b  = blockIdx.x & 7;
    const int qt = blockIdx.x >> 3;
    const long long rowQ0 = (long long)b * L_ + (long long)qt * 64;
    const long long rowB0 = (long long)b * L_;

    const int rtq = w >> 1;
    const int ch  = w & 1;

    bf16x8 qf[4];
    {
        const ushort* qrow = qk + (rowQ0 + rtq * 16 + li) * 256;
#pragma unroll
        for (int ks = 0; ks < 4; ++ks)
            qf[ks] = *(const bf16x8*)&qrow[ks * 32 + g * 8];
    }

    float l_part[4] = {0.f, 0.f, 0.f, 0.f};

    f32x4 o[4][6];
#pragma unroll
    for (int rt = 0; rt < 4; ++rt)
#pragma unroll
        for (int ct = 0; ct < 6; ++ct)
            o[rt][ct] = (f32x4){0.f, 0.f, 0.f, 0.f};

    const ushort* vrow = vT + ((size_t)b * 768 + w * 96 + li) * 2048 + g * 8;

    const int kr  = t >> 4;
    const int c16 = t & 15;
    const int ksw = (c16 * 16) ^ ((kr & 7) << 4);

    uint4 kA = *(const uint4*)&qk[(rowB0 + kr)      * 256 + 128 + c16 * 8];
    uint4 kB = *(const uint4*)&qk[(rowB0 + kr + 32) * 256 + 128 + c16 * 8];
    uint4 kC = *(const uint4*)&qk[(rowB0 + kr + 64) * 256 + 128 + c16 * 8];
    uint4 kD = *(const uint4*)&qk[(rowB0 + kr + 96) * 256 + 128 + c16 * 8];

    union U16 { uint4 u; bf16x8 bv; };

    for (int jt = 0; jt < 16; ++jt) {
        *(uint4*)&KbB[(kr)      * 256 + ksw] = kA;
        *(uint4*)&KbB[(kr + 32) * 256 + ksw] = kB;
        *(uint4*)&KbB[(kr + 64) * 256 + ksw] = kC;
        *(uint4*)&KbB[(kr + 96) * 256 + ksw] = kD;
        __syncthreads();   // (A)

        if (jt + 1 < 16) {
            const ushort* kn = qk + (rowB0 + (jt + 1) * 128) * 256 + 128 + c16 * 8;
            kA = *(const uint4*)(kn + (size_t)(kr)      * 256);
            kB = *(const uint4*)(kn + (size_t)(kr + 32) * 256);
            kC = *(const uint4*)(kn + (size_t)(kr + 64) * 256);
            kD = *(const uint4*)(kn + (size_t)(kr + 96) * 256);
        }

#pragma unroll
        for (int ci = 0; ci < 4; ++ci) {
            const int ct = ch * 4 + ci;
            const int krow = ct * 16 + li;
            const int rs = (krow & 7) << 4;
            f32x4 s = {0.f, 0.f, 0.f, 0.f};
#pragma unroll
            for (int ks = 0; ks < 4; ++ks) {
                bf16x8 kf = *(const bf16x8*)&KbB[krow * 256 + ((ks * 64 + g * 16) ^ rs)];
                s = __builtin_amdgcn_mfma_f32_16x16x32_bf16(qf[ks], kf, s, 0, 0, 0);
            }
#pragma unroll
            for (int r = 0; r < 4; ++r) {
                float p = __expf(SCALE * s[r]);
                l_part[r] += p;
                const int prow = rtq * 16 + g * 4 + r;
                *(ushort*)&PbB[prow * 256 + (((ct * 16 + li) * 2) ^ ((prow & 7) << 4))]
                    = (ushort)bfr(p);
            }
        }
        __syncthreads();   // (C)

        const ushort* vj = vrow + jt * 128;
#pragma unroll
        for (int ks = 0; ks < 4; ++ks) {
            bf16x8 pa0 = *(const bf16x8*)&PbB[(0 * 16 + li) * 256 + ((ks * 64 + g * 16) ^ ((li & 7) << 4))];
            bf16x8 pa1 = *(const bf16x8*)&PbB[(1 * 16 + li) * 256 + ((ks * 64 + g * 16) ^ ((li & 7) << 4))];
            bf16x8 pa2 = *(const bf16x8*)&PbB[(2 * 16 + li) * 256 + ((ks * 64 + g * 16) ^ ((li & 7) << 4))];
            bf16x8 pa3 = *(const bf16x8*)&PbB[(3 * 16 + li) * 256 + ((ks * 64 + g * 16) ^ ((li & 7) << 4))];
            U16 vc0, vc1, vc2, vc3, vc4, vc5;
            vc0.u = *(const uint4*)(vj + (size_t)(0 * 16) * 2048 + ks * 32);
            vc1.u = *(const uint4*)(vj + (size_t)(1 * 16) * 2048 + ks * 32);
            vc2.u = *(const uint4*)(vj + (size_t)(2 * 16) * 2048 + ks * 32);
            vc3.u = *(const uint4*)(vj + (size_t)(3 * 16) * 2048 + ks * 32);
            vc4.u = *(const uint4*)(vj + (size_t)(4 * 16) * 2048 + ks * 32);
            vc5.u = *(const uint4*)(vj + (size_t)(5 * 16) * 2048 + ks * 32);
#define PV_CT(CT, VC) \
            o[0][CT] = __builtin_amdgcn_mfma_f32_16x16x32_bf16(pa0, VC.bv, o[0][CT], 0, 0, 0); \
            o[1][CT] = __builtin_amdgcn_mfma_f32_16x16x32_bf16(pa1, VC.bv, o[1][CT], 0, 0, 0); \
            o[2][CT] = __builtin_amdgcn_mfma_f32_16x16x32_bf16(pa2, VC.bv, o[2][CT], 0, 0, 0); \
            o[3][CT] = __builtin_amdgcn_mfma_f32_16x16x32_bf16(pa3, VC.bv, o[3][CT], 0, 0, 0);
            PV_CT(0, vc0)
            PV_CT(1, vc1)
            PV_CT(2, vc2)
            PV_CT(3, vc3)
            PV_CT(4, vc4)
            PV_CT(5, vc5)
#undef PV_CT
        }
    }

#pragma unroll
    for (int r = 0; r < 4; ++r) {
#pragma unroll
        for (int off = 8; off >= 1; off >>= 1)
            l_part[r] += __shfl_xor(l_part[r], off);
    }
    if (li == 0) {
#pragma unroll
        for (int r = 0; r < 4; ++r)
            lred[ch][rtq * 16 + g * 4 + r] = l_part[r];
    }
    __syncthreads();

    // ---- finalize: /l, gate by u (read-only), write bf16 gated ----
#pragma unroll
    for (int rt = 0; rt < 4; ++rt) {
#pragma unroll
        for (int r = 0; r < 4; ++r) {
            const int row = rt * 16 + g * 4 + r;
            float inv = 1.0f / (lred[0][row] + lred[1][row]);
            const float* ub = u_buf + (rowQ0 + row) * 768;
            ushort* gb = gated + (rowQ0 + row) * 768;
#pragma unroll
            for (int ct = 0; ct < 6; ++ct) {
                int col = w * 96 + ct * 16 + li;
                gb[col] = (ushort)bfr(o[rt][ct][r] * inv * ub[col]);
            }
        }
    }
}

extern "C" void kernel_launch(void* const* d_in, const int* in_sizes, int n_in,
                              void* d_out, int out_size, void* d_ws, size_t ws_size,
                              hipStream_t stream)
{
    const float* x    = (const float*)d_in[0];   // [8,2048,384]
    const float* pos  = (const float*)d_in[1];   // [1,2048,256]
    const float* Wuv  = (const float*)d_in[2];   // [384,1792]
    const float* Wout = (const float*)d_in[3];   // [768,384]
    float* out = (float*)d_out;                  // [8,2048,384] f32

    float*  u_buf = (float*)d_ws;                        // 16384*768 f32   (50.3 MB)
    ushort* qk    = (ushort*)(u_buf + (size_t)R_ * HID); // 16384*256 bf16  (8.4 MB)
    ushort* vT    = qk + (size_t)R_ * 256;               // 8*768*2048 bf16 (25.2 MB)
    ushort* WuvThi  = vT + (size_t)B_ * HID * L_;
    ushort* WuvTlo  = WuvThi + (size_t)NUV * D2;
    ushort* WoutThi = WuvTlo + (size_t)NUV * D2;
    ushort* WoutTlo = WoutThi + (size_t)D2 * HID;
    // shared region: xhi (16384*384, dead after gemm1) aliased under
    // gated (16384*768, written by attn, read by gemm2)
    ushort* gated   = WoutTlo + (size_t)D2 * HID;        // 16384*768 bf16 (25.2 MB)
    ushort* xhi     = gated;                             // 16384*384 bf16 (alias)

    size_t need = ((size_t)R_ * HID) * 4 +
                  ((size_t)R_ * 256 + (size_t)B_ * HID * L_ +
                   2 * (size_t)NUV * D2 + 2 * (size_t)D2 * HID +
                   (size_t)R_ * HID) * 2;                // 113.0 MB
    if (ws_size < need) return;

    conv_w<<<dim3((D2 * NUV + 255) / 256), dim3(256), 0, stream>>>(Wuv, WuvThi, WuvTlo, D2, NUV);
    conv_w<<<dim3((HID * D2 + 255) / 256), dim3(256), 0, stream>>>(Wout, WoutThi, WoutTlo, HID, D2);
    conv_x<<<dim3((R_ * D2 + 255) / 256), dim3(256), 0, stream>>>(x, xhi, R_ * D2);

    // GEMM1: 2-pass, GAU epilogue (reads xhi; xhi dead afterwards)
    gemm_2p<1><<<dim3(NUV / 128, R_ / 128), dim3(512), 0, stream>>>(
        xhi, D2, WuvThi, WuvTlo, D2, nullptr, 0, u_buf, qk, vT, D2);

    rope_bf<<<dim3(R_), dim3(128), 0, stream>>>(qk, pos);

    // attention + gate -> gated bf16 (overwrites xhi region, safe)
    fused_attn13<<<dim3(256), dim3(512), 0, stream>>>(u_buf, qk, vT, gated);

    // GEMM2: 2-pass, plain f32 C
    gemm_2p<0><<<dim3(D2 / 128, R_ / 128), dim3(512), 0, stream>>>(
        gated, HID, WoutThi, WoutTlo, HID, out, D2, nullptr, nullptr, nullptr, HID);
}